// Round 1
// baseline (1301.908 us; speedup 1.0000x reference)
//
#include <hip/hip_runtime.h>

typedef unsigned short u16;
typedef unsigned int u32;

#define B_TOTAL 65536
#define H 512
#define D 64
#define BM 64

typedef __bf16 bf16x8 __attribute__((ext_vector_type(8)));
typedef float f32x4 __attribute__((ext_vector_type(4)));

__device__ __forceinline__ u32 f2b(float f) {  // fp32 -> bf16 bits, RNE
  u32 u = __builtin_bit_cast(u32, f);
  return (u + 0x7fffu + ((u >> 16) & 1u)) >> 16;
}
__device__ __forceinline__ float b2f(u32 bits) {
  return __builtin_bit_cast(float, bits << 16);
}

// ---- workspace layout (bf16 element offsets) ----
#define OFF_Wz0b 0          /* [512][64]  fwd L0 */
#define OFF_Wx0b 32768      /* [512][64] */
#define OFF_Wx1b 65536
#define OFF_Wx2b 98304
#define OFF_Wz1b 131072     /* [512][512] fwd */
#define OFF_Wz2b 393216
#define OFF_Wz3b 655360
#define OFF_Wz1t 917504     /* [512][512] transposed, bwd */
#define OFF_Wz2t 1179648
#define OFF_Wz3t 1441792
#define OFF_Wz0t 1703936    /* [64][512] transposed */
#define OFF_Wx0t 1736704
#define OFF_Wx1t 1769472
#define OFF_Wx2t 1802240
#define OFF_WEND 1835008
#define SLAB_ELEMS (B_TOTAL * H)          /* 33,554,432 bf16 per sigmoid slab */
#define OFF_S0 OFF_WEND
#define OFF_S1 (OFF_S0 + SLAB_ELEMS)
#define OFF_S2 (OFF_S1 + SLAB_ELEMS)
#define WS_ELEMS (OFF_S2 + SLAB_ELEMS)    /* ~102.5M elems = ~205 MB */

// ---- weight prep: fp32 -> bf16, plus transposed copies ----
__global__ __launch_bounds__(256) void prep_kernel(
    const float* __restrict__ Wz0, const float* __restrict__ Wz1,
    const float* __restrict__ Wz2, const float* __restrict__ Wz3,
    const float* __restrict__ Wx0, const float* __restrict__ Wx1,
    const float* __restrict__ Wx2, u16* __restrict__ wsb) {
  int i = blockIdx.x * 256 + threadIdx.x;   // grid exactly covers OFF_WEND
  float v;
  if (i < 131072) {                          // Wz0b,Wx0b,Wx1b,Wx2b direct [512][64]
    const float* src = (i < 32768) ? Wz0 : (i < 65536) ? Wx0 : (i < 98304) ? Wx1 : Wx2;
    v = src[i & 32767];
  } else if (i < 917504) {                   // Wz1b,Wz2b,Wz3b direct [512][512]
    int j = i - 131072;
    const float* src = (j < 262144) ? Wz1 : (j < 524288) ? Wz2 : Wz3;
    v = src[j & 262143];
  } else if (i < 1703936) {                  // Wz1t..Wz3t: t[r][c] = W[c][r]
    int j = i - 917504;
    const float* src = (j < 262144) ? Wz1 : (j < 524288) ? Wz2 : Wz3;
    int k = j & 262143; int r = k >> 9, c = k & 511;
    v = src[c * 512 + r];
  } else {                                   // Wz0t,Wx0t,Wx1t,Wx2t: t[d][h] = W[h][d]
    int j = i - 1703936;
    const float* src = (j < 32768) ? Wz0 : (j < 65536) ? Wx0 : (j < 98304) ? Wx1 : Wx2;
    int k = j & 32767; int d = k >> 9, h = k & 511;
    v = src[h * 64 + d];
  }
  wsb[i] = (u16)f2b(v);
}

__global__ __launch_bounds__(256) void fill_sentinel(float* out, int n) {
  int i = blockIdx.x * 256 + threadIdx.x;
  if (i < n) out[i] = 12345.0f;   // unmistakable "workspace too small" marker
}

// ---- fused ICNN fwd+bwd ----
// block = 256 thr (4 waves), BM=64 batch rows; wave w owns cols [w*128, w*128+128)
// of every [64,512] GEMM (acc[4][8] tiles of 16x16), and cols [w*16,w*16+16) of
// the [64,64] grad GEMMs (gacc[4]).
__global__ __launch_bounds__(256, 2) void icnn_kernel(
    const float* __restrict__ state,
    const float* __restrict__ bz0, const float* __restrict__ bx0,
    const float* __restrict__ bx1, const float* __restrict__ bx2,
    const float* __restrict__ WzL, const float* __restrict__ WxL,
    u16* __restrict__ wsw, float* __restrict__ out) {
  // XOR-swizzled activation buffer: value(m,k) at chunk ((k>>3)^(m&7)), elem k&7.
  // Row stride 1024B; swizzle spreads the 16-lane A-frag column reads over all
  // bank groups -> 2-way max (free). 64 KB exactly.
  __shared__ u16 zbuf[BM * H];

  const int tid = threadIdx.x;
  const int w = tid >> 6;
  const int lane = tid & 63;
  const int l15 = lane & 15;
  const int q = lane >> 4;           // k-group / row-group within MFMA
  const int blk = blockIdx.x;
  const int blk4w = blk * 4 + w;

  const u16* Wz0b = wsw + OFF_Wz0b;
  const u16* Wx0b = wsw + OFF_Wx0b;
  const u16* Wx1b = wsw + OFF_Wx1b;
  const u16* Wx2b = wsw + OFF_Wx2b;
  const u16* Wz1b = wsw + OFF_Wz1b;
  const u16* Wz2b = wsw + OFF_Wz2b;
  const u16* Wz3b = wsw + OFF_Wz3b;
  const u16* Wz1t = wsw + OFF_Wz1t;
  const u16* Wz2t = wsw + OFF_Wz2t;
  const u16* Wz3t = wsw + OFF_Wz3t;
  const u16* Wz0t = wsw + OFF_Wz0t;
  const u16* Wx0t = wsw + OFF_Wx0t;
  const u16* Wx1t = wsw + OFF_Wx1t;
  const u16* Wx2t = wsw + OFF_Wx2t;
  uint2* slab0 = (uint2*)(wsw + OFF_S0);
  uint2* slab1 = (uint2*)(wsw + OFF_S1);
  uint2* slab2 = (uint2*)(wsw + OFF_S2);

  // x = state - 1, held in registers as A-fragments for all 4 x-GEMMs.
  bf16x8 xf[4][2];
#pragma unroll
  for (int mt = 0; mt < 4; ++mt) {
#pragma unroll
    for (int ks = 0; ks < 2; ++ks) {
      const float* p = state + (blk * BM + mt * 16 + l15) * D + ks * 32 + q * 8;
      f32x4 v0 = *(const f32x4*)(p);
      f32x4 v1 = *(const f32x4*)(p + 4);
      u16 t[8];
#pragma unroll
      for (int j = 0; j < 4; ++j) {
        t[j]     = (u16)f2b(v0[j] - 1.0f);
        t[4 + j] = (u16)f2b(v1[j] - 1.0f);
      }
      xf[mt][ks] = __builtin_bit_cast(bf16x8, *(ulonglong2*)t);
    }
  }

  f32x4 acc[4][8];
  f32x4 gacc[4];
#pragma unroll
  for (int mt = 0; mt < 4; ++mt) gacc[mt] = {0.f, 0.f, 0.f, 0.f};

  auto zeroacc = [&]() {
#pragma unroll
    for (int mt = 0; mt < 4; ++mt)
#pragma unroll
      for (int nt = 0; nt < 8; ++nt) acc[mt][nt] = {0.f, 0.f, 0.f, 0.f};
  };
  auto ldA = [&](int mrow, int step) -> bf16x8 {   // LDS A-frag (swizzled)
    int m = mrow + l15;
    int idx = m * H + (((step * 4 + q) ^ (m & 7)) << 3);
    return *(const bf16x8*)(&zbuf[idx]);
  };
  auto ldW = [&](const u16* Wp, int stride, int n, int k) -> bf16x8 {
    return *(const bf16x8*)(Wp + n * stride + k);
  };
  auto wrZ = [&](int row, int n, float v) {        // swizzled LDS bf16 write
    zbuf[row * H + ((((n >> 3) ^ (row & 7))) << 3) + (n & 7)] = (u16)f2b(v);
  };

  auto fwdH = [&](const u16* Wb) {                 // acc += zbuf @ W^T (K=512)
#pragma unroll 4
    for (int step = 0; step < 16; ++step) {
      bf16x8 a[4];
#pragma unroll
      for (int mt = 0; mt < 4; ++mt) a[mt] = ldA(mt * 16, step);
#pragma unroll
      for (int nt = 0; nt < 8; ++nt) {
        bf16x8 b = ldW(Wb, H, w * 128 + nt * 16 + l15, step * 32 + q * 8);
#pragma unroll
        for (int mt = 0; mt < 4; ++mt)
          acc[mt][nt] = __builtin_amdgcn_mfma_f32_16x16x32_bf16(a[mt], b, acc[mt][nt], 0, 0, 0);
      }
    }
  };
  auto fwdX = [&](const u16* Wxb) {                // acc += x @ Wx^T (K=64)
#pragma unroll
    for (int ks = 0; ks < 2; ++ks)
#pragma unroll
      for (int nt = 0; nt < 8; ++nt) {
        bf16x8 b = ldW(Wxb, D, w * 128 + nt * 16 + l15, ks * 32 + q * 8);
#pragma unroll
        for (int mt = 0; mt < 4; ++mt)
          acc[mt][nt] = __builtin_amdgcn_mfma_f32_16x16x32_bf16(xf[mt][ks], b, acc[mt][nt], 0, 0, 0);
      }
  };
  auto bwdstep = [&](const u16* Wzt, const u16* Wgt) {  // acc=g, gacc+=d@Wg
#pragma unroll 4
    for (int step = 0; step < 16; ++step) {
      bf16x8 a[4];
#pragma unroll
      for (int mt = 0; mt < 4; ++mt) a[mt] = ldA(mt * 16, step);
#pragma unroll
      for (int nt = 0; nt < 8; ++nt) {
        bf16x8 b = ldW(Wzt, H, w * 128 + nt * 16 + l15, step * 32 + q * 8);
#pragma unroll
        for (int mt = 0; mt < 4; ++mt)
          acc[mt][nt] = __builtin_amdgcn_mfma_f32_16x16x32_bf16(a[mt], b, acc[mt][nt], 0, 0, 0);
      }
      bf16x8 bg = ldW(Wgt, H, w * 16 + l15, step * 32 + q * 8);
#pragma unroll
      for (int mt = 0; mt < 4; ++mt)
        gacc[mt] = __builtin_amdgcn_mfma_f32_16x16x32_bf16(a[mt], bg, gacc[mt], 0, 0, 0);
    }
  };

  // forward epilogue: a+=bias; z=softplus -> zbuf; s=sigmoid -> slab (C-layout private)
  auto fwd_epi = [&](const float* biasp, uint2* slab) {
#pragma unroll
    for (int mt = 0; mt < 4; ++mt)
#pragma unroll
      for (int nt = 0; nt < 8; ++nt) {
        int n = w * 128 + nt * 16 + l15;
        float bias = biasp[n];
        f32x4 A = acc[mt][nt];
        u32 sb[4];
#pragma unroll
        for (int r = 0; r < 4; ++r) {
          float a = A[r] + bias;
          float t = __expf(-a);            // branch-free: |a| <~ 12 here
          float u = 1.0f + t;
          float s = __builtin_amdgcn_rcpf(u);     // sigmoid(a)
          float z = a + __logf(u);                // softplus(a)
          sb[r] = f2b(s);
          wrZ(mt * 16 + q * 4 + r, n, z);
        }
        slab[(blk4w * 32 + mt * 8 + nt) * 64 + lane] =
            make_uint2(sb[0] | (sb[1] << 16), sb[2] | (sb[3] << 16));
      }
  };
  auto d3_epi = [&](const float* biasp) {   // d3 = WzL * sigmoid(a3) -> zbuf
#pragma unroll
    for (int mt = 0; mt < 4; ++mt)
#pragma unroll
      for (int nt = 0; nt < 8; ++nt) {
        int n = w * 128 + nt * 16 + l15;
        float bias = biasp[n];
        float wl = WzL[n];
        f32x4 A = acc[mt][nt];
#pragma unroll
        for (int r = 0; r < 4; ++r) {
          float a = A[r] + bias;
          float t = __expf(-a);
          float s = __builtin_amdgcn_rcpf(1.0f + t);
          wrZ(mt * 16 + q * 4 + r, n, wl * s);
        }
      }
  };
  auto bwd_epi = [&](const uint2* slab) {   // d = g * s -> zbuf
#pragma unroll
    for (int mt = 0; mt < 4; ++mt)
#pragma unroll
      for (int nt = 0; nt < 8; ++nt) {
        uint2 v = slab[(blk4w * 32 + mt * 8 + nt) * 64 + lane];
        float ss[4] = {b2f(v.x & 0xffffu), b2f(v.x >> 16),
                       b2f(v.y & 0xffffu), b2f(v.y >> 16)};
        int n = w * 128 + nt * 16 + l15;
        f32x4 A = acc[mt][nt];
#pragma unroll
        for (int r = 0; r < 4; ++r) wrZ(mt * 16 + q * 4 + r, n, A[r] * ss[r]);
      }
  };

  // ---------------- forward ----------------
  zeroacc(); fwdX(Wz0b);                   // a0 = x@Wz0^T
  __syncthreads(); fwd_epi(bz0, slab0); __syncthreads();
  zeroacc(); fwdH(Wz1b); fwdX(Wx0b);       // a1 = z0@Wz1^T + x@Wx0^T
  __syncthreads(); fwd_epi(bx0, slab1); __syncthreads();
  zeroacc(); fwdH(Wz2b); fwdX(Wx1b);
  __syncthreads(); fwd_epi(bx1, slab2); __syncthreads();
  zeroacc(); fwdH(Wz3b); fwdX(Wx2b);
  __syncthreads(); d3_epi(bx2); __syncthreads();
  // ---------------- backward ----------------
  zeroacc(); bwdstep(Wz3t, Wx2t);          // g2 = d3@Wz3 ; grad += d3@Wx2
  __syncthreads(); bwd_epi(slab2); __syncthreads();
  zeroacc(); bwdstep(Wz2t, Wx1t);          // g1 ; grad += d2@Wx1
  __syncthreads(); bwd_epi(slab1); __syncthreads();
  zeroacc(); bwdstep(Wz1t, Wx0t);          // g0 ; grad += d1@Wx0
  __syncthreads(); bwd_epi(slab0); __syncthreads();
#pragma unroll 4
  for (int step = 0; step < 16; ++step) {  // grad += d0@Wz0
    bf16x8 a[4];
#pragma unroll
    for (int mt = 0; mt < 4; ++mt) a[mt] = ldA(mt * 16, step);
    bf16x8 bg = ldW(Wz0t, H, w * 16 + l15, step * 32 + q * 8);
#pragma unroll
    for (int mt = 0; mt < 4; ++mt)
      gacc[mt] = __builtin_amdgcn_mfma_f32_16x16x32_bf16(a[mt], bg, gacc[mt], 0, 0, 0);
  }
  // store: out[b][d] = gacc + WxL[d]
  int n2 = w * 16 + l15;
  float wx = WxL[n2];
#pragma unroll
  for (int mt = 0; mt < 4; ++mt)
#pragma unroll
    for (int r = 0; r < 4; ++r)
      out[(blk * BM + mt * 16 + q * 4 + r) * D + n2] = gacc[mt][r] + wx;
}

extern "C" void kernel_launch(void* const* d_in, const int* in_sizes, int n_in,
                              void* d_out, int out_size, void* d_ws, size_t ws_size,
                              hipStream_t stream) {
  const float* state = (const float*)d_in[0];
  const float* Wz0 = (const float*)d_in[1];
  const float* bz0 = (const float*)d_in[2];
  const float* Wz1 = (const float*)d_in[3];
  const float* Wz2 = (const float*)d_in[4];
  const float* Wz3 = (const float*)d_in[5];
  const float* WzL = (const float*)d_in[6];
  const float* Wx0 = (const float*)d_in[7];
  const float* bx0 = (const float*)d_in[8];
  const float* Wx1 = (const float*)d_in[9];
  const float* bx1 = (const float*)d_in[10];
  const float* Wx2 = (const float*)d_in[11];
  const float* bx2 = (const float*)d_in[12];
  const float* WxL = (const float*)d_in[13];

  if (ws_size < (size_t)WS_ELEMS * 2) {
    // ws too small for sigmoid slabs -> emit sentinel so the failure is diagnosable
    fill_sentinel<<<(out_size + 255) / 256, 256, 0, stream>>>((float*)d_out, out_size);
    return;
  }
  u16* wsw = (u16*)d_ws;
  prep_kernel<<<OFF_WEND / 256, 256, 0, stream>>>(Wz0, Wz1, Wz2, Wz3, Wx0, Wx1, Wx2, wsw);
  icnn_kernel<<<B_TOTAL / BM, 256, 0, stream>>>(state, bz0, bx0, bx1, bx2, WzL, WxL,
                                                wsw, (float*)d_out);
}

// Round 2
// 1183.774 us; speedup vs baseline: 1.0998x; 1.0998x over previous
//
#include <hip/hip_runtime.h>

typedef unsigned short u16;
typedef unsigned int u32;

#define B_TOTAL 65536
#define H 512
#define D 64
#define BM 64

typedef __bf16 bf16x8 __attribute__((ext_vector_type(8)));
typedef float f32x4 __attribute__((ext_vector_type(4)));

__device__ __forceinline__ u32 f2b(float f) {  // fp32 -> bf16 bits, RNE
  u32 u = __builtin_bit_cast(u32, f);
  return (u + 0x7fffu + ((u >> 16) & 1u)) >> 16;
}
__device__ __forceinline__ float b2f(u32 bits) {
  return __builtin_bit_cast(float, bits << 16);
}

// ---- workspace layout (bf16 element offsets) ----
// All weight regions are FRAGMENT-PACKED: for logical B-matrix M[NN][KK],
// packed[( (n>>4)*(KK/32) + (k>>5) )*512 + lane*8 + j] = M[n][k]
// with n = ntile*16 + (lane&15), k = kstep*32 + (lane>>4)*8 + j.
// One B-fragment load = 64 lanes x 16 B fully coalesced (1 KB).
#define OFF_Wz0b 0          /* [N=512][K=64]  fwd L0 */
#define OFF_Wx0b 32768
#define OFF_Wx1b 65536
#define OFF_Wx2b 98304
#define OFF_Wz1b 131072     /* [N=512][K=512] fwd */
#define OFF_Wz2b 393216
#define OFF_Wz3b 655360
#define OFF_Wz1t 917504     /* [N=512][K=512] transposed, bwd */
#define OFF_Wz2t 1179648
#define OFF_Wz3t 1441792
#define OFF_Wz0t 1703936    /* [N=64][K=512] transposed grad weights */
#define OFF_Wx0t 1736704
#define OFF_Wx1t 1769472
#define OFF_Wx2t 1802240
#define OFF_WEND 1835008
#define SLAB_ELEMS (B_TOTAL * H)          /* 33,554,432 bf16 per sigmoid slab */
#define OFF_S0 OFF_WEND
#define OFF_S1 (OFF_S0 + SLAB_ELEMS)
#define OFF_S2 (OFF_S1 + SLAB_ELEMS)
#define WS_ELEMS (OFF_S2 + SLAB_ELEMS)    /* ~102.5M elems = ~205 MB */

// ---- weight prep: fp32 -> bf16, fragment-packed (+ transposed variants) ----
__global__ __launch_bounds__(256) void prep_kernel(
    const float* __restrict__ Wz0, const float* __restrict__ Wz1,
    const float* __restrict__ Wz2, const float* __restrict__ Wz3,
    const float* __restrict__ Wx0, const float* __restrict__ Wx1,
    const float* __restrict__ Wx2, u16* __restrict__ wsb) {
  int i = blockIdx.x * 256 + threadIdx.x;   // grid exactly covers OFF_WEND
  const float* src;
  int NN, KK, trans, p;
  if (i < 131072) {                          // x-path fwd: [512][64] direct
    int r = i >> 15; p = i & 32767;
    src = (r == 0) ? Wz0 : (r == 1) ? Wx0 : (r == 2) ? Wx1 : Wx2;
    NN = 512; KK = 64; trans = 0;
  } else if (i < 917504) {                   // H fwd: [512][512] direct
    int j = i - 131072; int r = j >> 18; p = j & 262143;
    src = (r == 0) ? Wz1 : (r == 1) ? Wz2 : Wz3;
    NN = 512; KK = 512; trans = 0;
  } else if (i < 1703936) {                  // H bwd: transposed
    int j = i - 917504; int r = j >> 18; p = j & 262143;
    src = (r == 0) ? Wz1 : (r == 1) ? Wz2 : Wz3;
    NN = 512; KK = 512; trans = 1;
  } else {                                   // grad weights: [64][512] = W^T
    int j = i - 1703936; int r = j >> 15; p = j & 32767;
    src = (r == 0) ? Wz0 : (r == 1) ? Wx0 : (r == 2) ? Wx1 : Wx2;
    NN = 64; KK = 512; trans = 1;
  }
  int jj = p & 7, lane = (p >> 3) & 63, blk = p >> 9;
  int kt_sh = (KK == 64) ? 1 : 4;            // log2(KK/32)
  int ntile = blk >> kt_sh;
  int kstep = blk & ((1 << kt_sh) - 1);
  int n = ntile * 16 + (lane & 15);
  int k = kstep * 32 + ((lane >> 4) << 3) + jj;
  float v = trans ? src[k * NN + n] : src[n * KK + k];
  wsb[i] = (u16)f2b(v);
}

__global__ __launch_bounds__(256) void fill_sentinel(float* out, int n) {
  int i = blockIdx.x * 256 + threadIdx.x;
  if (i < n) out[i] = 12345.0f;   // unmistakable "workspace too small" marker
}

// ---- fused ICNN fwd+bwd ----
// block = 256 thr (4 waves), BM=64 batch rows; wave w owns cols [w*128, w*128+128)
// of every [64,512] GEMM (acc[4][8]) and cols [w*16,w*16+16) of grad (gacc[4]).
// Weight B-frags: coalesced packed loads, software-pipelined 1 step deep.
__global__ __launch_bounds__(256, 2) void icnn_kernel(
    const float* __restrict__ state,
    const float* __restrict__ bz0, const float* __restrict__ bx0,
    const float* __restrict__ bx1, const float* __restrict__ bx2,
    const float* __restrict__ WzL, const float* __restrict__ WxL,
    u16* __restrict__ wsw, float* __restrict__ out) {
  // XOR-swizzled activation buffer (64 KB) + padded x buffer (9 KB).
  __shared__ u16 zbuf[BM * H];
  __shared__ u16 xbuf[BM * 72];   // row stride 72 elems = 144 B (16B-aligned, 2-way banks)

  const int tid = threadIdx.x;
  const int w = tid >> 6;
  const int lane = tid & 63;
  const int l15 = lane & 15;
  const int q = lane >> 4;
  const int blk = blockIdx.x;
  const int blk4w = blk * 4 + w;

  const u16* Wz0b = wsw + OFF_Wz0b;
  const u16* Wx0b = wsw + OFF_Wx0b;
  const u16* Wx1b = wsw + OFF_Wx1b;
  const u16* Wx2b = wsw + OFF_Wx2b;
  const u16* Wz1b = wsw + OFF_Wz1b;
  const u16* Wz2b = wsw + OFF_Wz2b;
  const u16* Wz3b = wsw + OFF_Wz3b;
  const u16* Wz1t = wsw + OFF_Wz1t;
  const u16* Wz2t = wsw + OFF_Wz2t;
  const u16* Wz3t = wsw + OFF_Wz3t;
  const u16* Wz0t = wsw + OFF_Wz0t;
  const u16* Wx0t = wsw + OFF_Wx0t;
  const u16* Wx1t = wsw + OFF_Wx1t;
  const u16* Wx2t = wsw + OFF_Wx2t;
  uint2* slab0 = (uint2*)(wsw + OFF_S0);
  uint2* slab1 = (uint2*)(wsw + OFF_S1);
  uint2* slab2 = (uint2*)(wsw + OFF_S2);

  // ---- stage x = state-1 into xbuf (bf16, padded row-major) ----
  {
    int r = tid >> 2, c0 = (tid & 3) << 4;
    const float* p = state + (blk * BM + r) * D + c0;
    u32* dst = (u32*)&xbuf[r * 72 + c0];
#pragma unroll
    for (int i = 0; i < 4; ++i) {
      f32x4 v = *(const f32x4*)(p + i * 4);
      dst[i * 2]     = f2b(v[0] - 1.0f) | (f2b(v[1] - 1.0f) << 16);
      dst[i * 2 + 1] = f2b(v[2] - 1.0f) | (f2b(v[3] - 1.0f) << 16);
    }
  }

  f32x4 acc[4][8];
  f32x4 gacc[4];
#pragma unroll
  for (int mt = 0; mt < 4; ++mt) gacc[mt] = {0.f, 0.f, 0.f, 0.f};

  auto zeroacc = [&]() {
#pragma unroll
    for (int mt = 0; mt < 4; ++mt)
#pragma unroll
      for (int nt = 0; nt < 8; ++nt) acc[mt][nt] = {0.f, 0.f, 0.f, 0.f};
  };
  auto ldA = [&](int mrow, int step) -> bf16x8 {   // LDS A-frag (swizzled)
    int m = mrow + l15;
    int idx = m * H + (((step * 4 + q) ^ (m & 7)) << 3);
    return *(const bf16x8*)(&zbuf[idx]);
  };
  auto ldX = [&](int mt, int ks) -> bf16x8 {       // x A-frag from padded xbuf
    return *(const bf16x8*)(&xbuf[(mt * 16 + l15) * 72 + ks * 32 + q * 8]);
  };
  auto wrZ = [&](int row, int n, float v) {        // swizzled LDS bf16 write
    zbuf[row * H + ((((n >> 3) ^ (row & 7))) << 3) + (n & 7)] = (u16)f2b(v);
  };

  // acc += x @ Wx^T (K=64), packed weights: kt=2
  auto fwdX = [&](const u16* Wxp) {
    const u16* xb = Wxp + (w * 8) * 1024 + lane * 8;
    bf16x8 bx[2][8];
#pragma unroll
    for (int nt = 0; nt < 8; ++nt) {
      bx[0][nt] = *(const bf16x8*)(xb + nt * 1024);
      bx[1][nt] = *(const bf16x8*)(xb + nt * 1024 + 512);
    }
#pragma unroll
    for (int ks = 0; ks < 2; ++ks) {
      bf16x8 ax[4];
#pragma unroll
      for (int mt = 0; mt < 4; ++mt) ax[mt] = ldX(mt, ks);
#pragma unroll
      for (int nt = 0; nt < 8; ++nt)
#pragma unroll
        for (int mt = 0; mt < 4; ++mt)
          acc[mt][nt] = __builtin_amdgcn_mfma_f32_16x16x32_bf16(ax[mt], bx[ks][nt], acc[mt][nt], 0, 0, 0);
    }
  };

  // one K-step: consume bc, prefetch bn (step lds), 32 MFMA
  auto fhalf = [&](bf16x8 (&bc)[8], bf16x8 (&bn)[8], const u16* wb, int step, int lds) {
    bf16x8 a[4];
#pragma unroll
    for (int mt = 0; mt < 4; ++mt) a[mt] = ldA(mt * 16, step);
#pragma unroll
    for (int nt = 0; nt < 8; ++nt) bn[nt] = *(const bf16x8*)(wb + nt * 8192 + lds * 512);
#pragma unroll
    for (int nt = 0; nt < 8; ++nt)
#pragma unroll
      for (int mt = 0; mt < 4; ++mt)
        acc[mt][nt] = __builtin_amdgcn_mfma_f32_16x16x32_bf16(a[mt], bc[nt], acc[mt][nt], 0, 0, 0);
  };
  auto fwdH = [&](const u16* Wp) {                 // acc += zbuf @ W^T (K=512)
    const u16* wb = Wp + (w * 8) * 8192 + lane * 8;
    bf16x8 b0[8], b1[8];
#pragma unroll
    for (int nt = 0; nt < 8; ++nt) b0[nt] = *(const bf16x8*)(wb + nt * 8192);
    for (int st = 0; st < 16; st += 2) {
      fhalf(b0, b1, wb, st, st + 1);
      fhalf(b1, b0, wb, st + 1, (st + 2 < 16) ? st + 2 : 0);
    }
  };

  auto bhalf = [&](bf16x8 (&bc)[8], bf16x8 (&bn)[8], const u16* wb, const u16* gb,
                   int step, int lds) {
    bf16x8 a[4];
#pragma unroll
    for (int mt = 0; mt < 4; ++mt) a[mt] = ldA(mt * 16, step);
#pragma unroll
    for (int nt = 0; nt < 8; ++nt) bn[nt] = *(const bf16x8*)(wb + nt * 8192 + lds * 512);
    bf16x8 g = *(const bf16x8*)(gb + step * 512);  // consumed last -> latency covered
#pragma unroll
    for (int nt = 0; nt < 8; ++nt)
#pragma unroll
      for (int mt = 0; mt < 4; ++mt)
        acc[mt][nt] = __builtin_amdgcn_mfma_f32_16x16x32_bf16(a[mt], bc[nt], acc[mt][nt], 0, 0, 0);
#pragma unroll
    for (int mt = 0; mt < 4; ++mt)
      gacc[mt] = __builtin_amdgcn_mfma_f32_16x16x32_bf16(a[mt], g, gacc[mt], 0, 0, 0);
  };
  auto bwdstep = [&](const u16* Wzt, const u16* Wgt) {  // acc=d@Wz, gacc+=d@Wg
    const u16* wb = Wzt + (w * 8) * 8192 + lane * 8;
    const u16* gb = Wgt + (w * 16) * 512 + lane * 8;
    bf16x8 b0[8], b1[8];
#pragma unroll
    for (int nt = 0; nt < 8; ++nt) b0[nt] = *(const bf16x8*)(wb + nt * 8192);
    for (int st = 0; st < 16; st += 2) {
      bhalf(b0, b1, wb, gb, st, st + 1);
      bhalf(b1, b0, wb, gb, st + 1, (st + 2 < 16) ? st + 2 : 0);
    }
  };

  // forward epilogue: a+=bias; z=softplus -> zbuf; s=sigmoid -> slab (lane-private)
  auto fwd_epi = [&](const float* biasp, uint2* slab) {
#pragma unroll
    for (int mt = 0; mt < 4; ++mt)
#pragma unroll
      for (int nt = 0; nt < 8; ++nt) {
        int n = w * 128 + nt * 16 + l15;
        float bias = biasp[n];
        f32x4 A = acc[mt][nt];
        u32 sb[4];
#pragma unroll
        for (int r = 0; r < 4; ++r) {
          float a = A[r] + bias;
          float t = __expf(-a);
          float u = 1.0f + t;
          float s = __builtin_amdgcn_rcpf(u);     // sigmoid(a)
          float z = a + __logf(u);                // softplus(a)
          sb[r] = f2b(s);
          wrZ(mt * 16 + q * 4 + r, n, z);
        }
        slab[(blk4w * 32 + mt * 8 + nt) * 64 + lane] =
            make_uint2(sb[0] | (sb[1] << 16), sb[2] | (sb[3] << 16));
      }
  };
  auto d3_epi = [&](const float* biasp) {   // d3 = WzL * sigmoid(a3) -> zbuf
#pragma unroll
    for (int mt = 0; mt < 4; ++mt)
#pragma unroll
      for (int nt = 0; nt < 8; ++nt) {
        int n = w * 128 + nt * 16 + l15;
        float bias = biasp[n];
        float wl = WzL[n];
        f32x4 A = acc[mt][nt];
#pragma unroll
        for (int r = 0; r < 4; ++r) {
          float a = A[r] + bias;
          float t = __expf(-a);
          float s = __builtin_amdgcn_rcpf(1.0f + t);
          wrZ(mt * 16 + q * 4 + r, n, wl * s);
        }
      }
  };
  auto bwd_epi = [&](const uint2* slab) {   // d = g * s -> zbuf
#pragma unroll
    for (int mt = 0; mt < 4; ++mt)
#pragma unroll
      for (int nt = 0; nt < 8; ++nt) {
        uint2 v = slab[(blk4w * 32 + mt * 8 + nt) * 64 + lane];
        float ss[4] = {b2f(v.x & 0xffffu), b2f(v.x >> 16),
                       b2f(v.y & 0xffffu), b2f(v.y >> 16)};
        int n = w * 128 + nt * 16 + l15;
        f32x4 A = acc[mt][nt];
#pragma unroll
        for (int r = 0; r < 4; ++r) wrZ(mt * 16 + q * 4 + r, n, A[r] * ss[r]);
      }
  };

  // ---------------- forward ----------------
  zeroacc();
  __syncthreads();                          // xbuf ready
  fwdX(Wz0b);                               // a0 = x@Wz0^T
  __syncthreads(); fwd_epi(bz0, slab0); __syncthreads();
  zeroacc(); fwdH(Wz1b); fwdX(Wx0b);        // a1 = z0@Wz1^T + x@Wx0^T
  __syncthreads(); fwd_epi(bx0, slab1); __syncthreads();
  zeroacc(); fwdH(Wz2b); fwdX(Wx1b);
  __syncthreads(); fwd_epi(bx1, slab2); __syncthreads();
  zeroacc(); fwdH(Wz3b); fwdX(Wx2b);
  __syncthreads(); d3_epi(bx2); __syncthreads();
  // ---------------- backward ----------------
  zeroacc(); bwdstep(Wz3t, Wx2t);           // g2 = d3@Wz3 ; grad += d3@Wx2
  __syncthreads(); bwd_epi(slab2); __syncthreads();
  zeroacc(); bwdstep(Wz2t, Wx1t);
  __syncthreads(); bwd_epi(slab1); __syncthreads();
  zeroacc(); bwdstep(Wz1t, Wx0t);
  __syncthreads(); bwd_epi(slab0); __syncthreads();
  {                                         // grad += d0@Wz0 (pipelined g-frags)
    const u16* gb = Wz0t + (w * 16) * 512 + lane * 8;
    bf16x8 g0 = *(const bf16x8*)(gb);
#pragma unroll 2
    for (int st = 0; st < 16; ++st) {
      bf16x8 a[4];
#pragma unroll
      for (int mt = 0; mt < 4; ++mt) a[mt] = ldA(mt * 16, st);
      bf16x8 g1 = *(const bf16x8*)(gb + ((st + 1 < 16) ? st + 1 : 0) * 512);
#pragma unroll
      for (int mt = 0; mt < 4; ++mt)
        gacc[mt] = __builtin_amdgcn_mfma_f32_16x16x32_bf16(a[mt], g0, gacc[mt], 0, 0, 0);
      g0 = g1;
    }
  }
  // store: out[b][d] = gacc + WxL[d]
  int n2 = w * 16 + l15;
  float wx = WxL[n2];
#pragma unroll
  for (int mt = 0; mt < 4; ++mt)
#pragma unroll
    for (int r = 0; r < 4; ++r)
      out[(blk * BM + mt * 16 + q * 4 + r) * D + n2] = gacc[mt][r] + wx;
}

extern "C" void kernel_launch(void* const* d_in, const int* in_sizes, int n_in,
                              void* d_out, int out_size, void* d_ws, size_t ws_size,
                              hipStream_t stream) {
  const float* state = (const float*)d_in[0];
  const float* Wz0 = (const float*)d_in[1];
  const float* bz0 = (const float*)d_in[2];
  const float* Wz1 = (const float*)d_in[3];
  const float* Wz2 = (const float*)d_in[4];
  const float* Wz3 = (const float*)d_in[5];
  const float* WzL = (const float*)d_in[6];
  const float* Wx0 = (const float*)d_in[7];
  const float* bx0 = (const float*)d_in[8];
  const float* Wx1 = (const float*)d_in[9];
  const float* bx1 = (const float*)d_in[10];
  const float* Wx2 = (const float*)d_in[11];
  const float* bx2 = (const float*)d_in[12];
  const float* WxL = (const float*)d_in[13];

  if (ws_size < (size_t)WS_ELEMS * 2) {
    fill_sentinel<<<(out_size + 255) / 256, 256, 0, stream>>>((float*)d_out, out_size);
    return;
  }
  u16* wsw = (u16*)d_ws;
  prep_kernel<<<OFF_WEND / 256, 256, 0, stream>>>(Wz0, Wz1, Wz2, Wz3, Wx0, Wx1, Wx2, wsw);
  icnn_kernel<<<B_TOTAL / BM, 256, 0, stream>>>(state, bz0, bx0, bx1, bx2, WzL, WxL,
                                                wsw, (float*)d_out);
}

// Round 3
// 948.539 us; speedup vs baseline: 1.3725x; 1.2480x over previous
//
#include <hip/hip_runtime.h>

typedef unsigned short u16;
typedef unsigned int u32;
typedef unsigned long long u64;

#define B_TOTAL 65536
#define H 512
#define D 64
#define BM 64

typedef __bf16 bf16x8 __attribute__((ext_vector_type(8)));
typedef float f32x4 __attribute__((ext_vector_type(4)));

__device__ __forceinline__ u32 f2b(float f) {  // fp32 -> bf16 bits, RNE
  u32 u = __builtin_bit_cast(u32, f);
  return (u + 0x7fffu + ((u >> 16) & 1u)) >> 16;
}
__device__ __forceinline__ float b2f(u32 bits) {
  return __builtin_bit_cast(float, bits << 16);
}

// ---- workspace layout (bf16 element offsets) ----
// Weight regions are FRAGMENT-PACKED: for logical B-matrix M[NN][KK],
// packed[( (n>>4)*(KK/32) + (k>>5) )*512 + lane*8 + j] = M[n][k],
// n = ntile*16 + (lane&15), k = kstep*32 + (lane>>4)*8 + j.
// One B-fragment load = 64 lanes x 16 B fully coalesced (1 KB).
#define OFF_Wz0b 0          /* [N=512][K=64]  fwd L0 */
#define OFF_Wx0b 32768
#define OFF_Wx1b 65536
#define OFF_Wx2b 98304
#define OFF_Wz1b 131072     /* [N=512][K=512] fwd */
#define OFF_Wz2b 393216
#define OFF_Wz3b 655360
#define OFF_Wz1t 917504     /* [N=512][K=512] transposed, bwd */
#define OFF_Wz2t 1179648
#define OFF_Wz3t 1441792
#define OFF_Wz0t 1703936    /* [N=64][K=512] transposed grad weights */
#define OFF_Wx0t 1736704
#define OFF_Wx1t 1769472
#define OFF_Wx2t 1802240
#define OFF_WEND 1835008
#define SLAB_ELEMS (B_TOTAL * H)          /* 33,554,432 bf16 per sigmoid slab */
#define OFF_S0 OFF_WEND
#define OFF_S1 (OFF_S0 + SLAB_ELEMS)
#define OFF_S2 (OFF_S1 + SLAB_ELEMS)
#define WS_ELEMS (OFF_S2 + SLAB_ELEMS)    /* ~102.5M elems = ~205 MB */

// ---- weight prep: fp32 -> bf16, fragment-packed (+ transposed variants) ----
__global__ __launch_bounds__(256) void prep_kernel(
    const float* __restrict__ Wz0, const float* __restrict__ Wz1,
    const float* __restrict__ Wz2, const float* __restrict__ Wz3,
    const float* __restrict__ Wx0, const float* __restrict__ Wx1,
    const float* __restrict__ Wx2, u16* __restrict__ wsb) {
  int i = blockIdx.x * 256 + threadIdx.x;   // grid exactly covers OFF_WEND
  const float* src;
  int NN, KK, trans, p;
  if (i < 131072) {                          // x-path fwd: [512][64] direct
    int r = i >> 15; p = i & 32767;
    src = (r == 0) ? Wz0 : (r == 1) ? Wx0 : (r == 2) ? Wx1 : Wx2;
    NN = 512; KK = 64; trans = 0;
  } else if (i < 917504) {                   // H fwd: [512][512] direct
    int j = i - 131072; int r = j >> 18; p = j & 262143;
    src = (r == 0) ? Wz1 : (r == 1) ? Wz2 : Wz3;
    NN = 512; KK = 512; trans = 0;
  } else if (i < 1703936) {                  // H bwd: transposed
    int j = i - 917504; int r = j >> 18; p = j & 262143;
    src = (r == 0) ? Wz1 : (r == 1) ? Wz2 : Wz3;
    NN = 512; KK = 512; trans = 1;
  } else {                                   // grad weights: [64][512] = W^T
    int j = i - 1703936; int r = j >> 15; p = j & 32767;
    src = (r == 0) ? Wz0 : (r == 1) ? Wx0 : (r == 2) ? Wx1 : Wx2;
    NN = 64; KK = 512; trans = 1;
  }
  int jj = p & 7, lane = (p >> 3) & 63, blk = p >> 9;
  int kt_sh = (KK == 64) ? 1 : 4;            // log2(KK/32)
  int ntile = blk >> kt_sh;
  int kstep = blk & ((1 << kt_sh) - 1);
  int n = ntile * 16 + (lane & 15);
  int k = kstep * 32 + ((lane >> 4) << 3) + jj;
  float v = trans ? src[k * NN + n] : src[n * KK + k];
  wsb[i] = (u16)f2b(v);
}

__global__ __launch_bounds__(256) void fill_sentinel(float* out, int n) {
  int i = blockIdx.x * 256 + threadIdx.x;
  if (i < n) out[i] = 12345.0f;   // unmistakable "workspace too small" marker
}

// ---- fused ICNN fwd+bwd ----
// block = 256 thr (4 waves), BM=64 rows; wave w owns cols [w*128,+128) of the
// [64,512] GEMMs (acc[4][8]) and cols [w*16,+16) of grad (gacc[4]).
// Half-step pipelined weight loads (bA[4]/bB[4], 32 VGPR) keep total register
// demand ~235 < 256 (2 waves/SIMD) -> no scratch spill.
// Slabs/state/out use non-temporal ops so streaming doesn't evict weights from L2.
__global__ __launch_bounds__(256, 2) void icnn_kernel(
    const float* __restrict__ state,
    const float* __restrict__ bz0, const float* __restrict__ bx0,
    const float* __restrict__ bx1, const float* __restrict__ bx2,
    const float* __restrict__ WzL, const float* __restrict__ WxL,
    u16* __restrict__ wsw, float* __restrict__ out) {
  __shared__ u16 zbuf[BM * H];    // XOR-swizzled activations, 64 KB
  __shared__ u16 xbuf[BM * 72];   // x staging, row stride 144 B

  const int tid = threadIdx.x;
  const int w = tid >> 6;
  const int lane = tid & 63;
  const int l15 = lane & 15;
  const int q = lane >> 4;
  const int blk = blockIdx.x;
  const int blk4w = blk * 4 + w;

  const u16* Wz0b = wsw + OFF_Wz0b;
  const u16* Wx0b = wsw + OFF_Wx0b;
  const u16* Wx1b = wsw + OFF_Wx1b;
  const u16* Wx2b = wsw + OFF_Wx2b;
  const u16* Wz1b = wsw + OFF_Wz1b;
  const u16* Wz2b = wsw + OFF_Wz2b;
  const u16* Wz3b = wsw + OFF_Wz3b;
  const u16* Wz1t = wsw + OFF_Wz1t;
  const u16* Wz2t = wsw + OFF_Wz2t;
  const u16* Wz3t = wsw + OFF_Wz3t;
  const u16* Wz0t = wsw + OFF_Wz0t;
  const u16* Wx0t = wsw + OFF_Wx0t;
  const u16* Wx1t = wsw + OFF_Wx1t;
  const u16* Wx2t = wsw + OFF_Wx2t;
  u64* slab0 = (u64*)(wsw + OFF_S0);
  u64* slab1 = (u64*)(wsw + OFF_S1);
  u64* slab2 = (u64*)(wsw + OFF_S2);

  // ---- stage x = state-1 into xbuf (bf16, padded row-major) ----
  {
    int r = tid >> 2, c0 = (tid & 3) << 4;
    const float* p = state + (blk * BM + r) * D + c0;
    u32* dst = (u32*)&xbuf[r * 72 + c0];
#pragma unroll
    for (int i = 0; i < 4; ++i) {
      f32x4 v = __builtin_nontemporal_load((const f32x4*)(p + i * 4));
      dst[i * 2]     = f2b(v[0] - 1.0f) | (f2b(v[1] - 1.0f) << 16);
      dst[i * 2 + 1] = f2b(v[2] - 1.0f) | (f2b(v[3] - 1.0f) << 16);
    }
  }

  f32x4 acc[4][8];
  f32x4 gacc[4];
  const f32x4 Z = {0.f, 0.f, 0.f, 0.f};
#pragma unroll
  for (int mt = 0; mt < 4; ++mt) gacc[mt] = Z;

  auto ldA = [&](int mt, int step) -> bf16x8 {     // LDS A-frag (swizzled)
    int m = mt * 16 + l15;
    int idx = m * H + (((step * 4 + q) ^ (m & 7)) << 3);
    return *(const bf16x8*)(&zbuf[idx]);
  };
  auto ldX = [&](int mt, int ks) -> bf16x8 {       // x A-frag from padded xbuf
    return *(const bf16x8*)(&xbuf[(mt * 16 + l15) * 72 + ks * 32 + q * 8]);
  };
  auto wrZ = [&](int row, int n, float v) {        // swizzled LDS bf16 write
    zbuf[row * H + ((((n >> 3) ^ (row & 7))) << 3) + (n & 7)] = (u16)f2b(v);
  };

  // acc (+)= x @ Wx^T (K=64). zero_first: overwrite acc on ks==0.
  auto fwdX = [&](const u16* Wxp, bool zero_first) {
    const u16* xb = Wxp + (w * 8) * 1024 + lane * 8;
#pragma unroll
    for (int ks = 0; ks < 2; ++ks) {
      bf16x8 ax[4];
#pragma unroll
      for (int mt = 0; mt < 4; ++mt) ax[mt] = ldX(mt, ks);
#pragma unroll
      for (int half = 0; half < 2; ++half) {
        bf16x8 b4[4];
#pragma unroll
        for (int nt = 0; nt < 4; ++nt)
          b4[nt] = *(const bf16x8*)(xb + (half * 4 + nt) * 1024 + ks * 512);
#pragma unroll
        for (int nt = 0; nt < 4; ++nt)
#pragma unroll
          for (int mt = 0; mt < 4; ++mt) {
            f32x4 c = (zero_first && ks == 0) ? Z : acc[mt][half * 4 + nt];
            acc[mt][half * 4 + nt] =
                __builtin_amdgcn_mfma_f32_16x16x32_bf16(ax[mt], b4[nt], c, 0, 0, 0);
          }
      }
    }
  };

  // acc = zbuf @ W^T (K=512), zero-start. Half-step pipelined (bA/bB, 32 VGPR).
  auto fwdH = [&](const u16* Wp) {
    const u16* wb = Wp + (w * 8) * 8192 + lane * 8;
    bf16x8 bA[4], bB[4];
#pragma unroll
    for (int nt = 0; nt < 4; ++nt) bA[nt] = *(const bf16x8*)(wb + nt * 8192);
    // st = 0 peeled: C = 0
    {
      bf16x8 a[4];
#pragma unroll
      for (int mt = 0; mt < 4; ++mt) a[mt] = ldA(mt, 0);
#pragma unroll
      for (int nt = 0; nt < 4; ++nt) bB[nt] = *(const bf16x8*)(wb + (nt + 4) * 8192);
#pragma unroll
      for (int nt = 0; nt < 4; ++nt)
#pragma unroll
        for (int mt = 0; mt < 4; ++mt)
          acc[mt][nt] = __builtin_amdgcn_mfma_f32_16x16x32_bf16(a[mt], bA[nt], Z, 0, 0, 0);
#pragma unroll
      for (int nt = 0; nt < 4; ++nt) bA[nt] = *(const bf16x8*)(wb + nt * 8192 + 512);
#pragma unroll
      for (int nt = 0; nt < 4; ++nt)
#pragma unroll
        for (int mt = 0; mt < 4; ++mt)
          acc[mt][nt + 4] = __builtin_amdgcn_mfma_f32_16x16x32_bf16(a[mt], bB[nt], Z, 0, 0, 0);
    }
    for (int st = 1; st < 16; ++st) {
      bf16x8 a[4];
#pragma unroll
      for (int mt = 0; mt < 4; ++mt) a[mt] = ldA(mt, st);
#pragma unroll
      for (int nt = 0; nt < 4; ++nt)
        bB[nt] = *(const bf16x8*)(wb + (nt + 4) * 8192 + st * 512);
#pragma unroll
      for (int nt = 0; nt < 4; ++nt)
#pragma unroll
        for (int mt = 0; mt < 4; ++mt)
          acc[mt][nt] = __builtin_amdgcn_mfma_f32_16x16x32_bf16(a[mt], bA[nt], acc[mt][nt], 0, 0, 0);
      int sn = (st + 1 < 16) ? st + 1 : 0;
#pragma unroll
      for (int nt = 0; nt < 4; ++nt)
        bA[nt] = *(const bf16x8*)(wb + nt * 8192 + sn * 512);
#pragma unroll
      for (int nt = 0; nt < 4; ++nt)
#pragma unroll
        for (int mt = 0; mt < 4; ++mt)
          acc[mt][nt + 4] = __builtin_amdgcn_mfma_f32_16x16x32_bf16(a[mt], bB[nt], acc[mt][nt + 4], 0, 0, 0);
    }
  };

  // acc = d @ Wz (zero-start) ; gacc += d @ Wg. Same pipelining.
  auto bwdH = [&](const u16* Wzt, const u16* Wgt) {
    const u16* wb = Wzt + (w * 8) * 8192 + lane * 8;
    const u16* gb = Wgt + (w * 16) * 512 + lane * 8;
    bf16x8 bA[4], bB[4];
#pragma unroll
    for (int nt = 0; nt < 4; ++nt) bA[nt] = *(const bf16x8*)(wb + nt * 8192);
    {
      bf16x8 a[4];
#pragma unroll
      for (int mt = 0; mt < 4; ++mt) a[mt] = ldA(mt, 0);
#pragma unroll
      for (int nt = 0; nt < 4; ++nt) bB[nt] = *(const bf16x8*)(wb + (nt + 4) * 8192);
      bf16x8 g = *(const bf16x8*)(gb);
#pragma unroll
      for (int nt = 0; nt < 4; ++nt)
#pragma unroll
        for (int mt = 0; mt < 4; ++mt)
          acc[mt][nt] = __builtin_amdgcn_mfma_f32_16x16x32_bf16(a[mt], bA[nt], Z, 0, 0, 0);
#pragma unroll
      for (int nt = 0; nt < 4; ++nt) bA[nt] = *(const bf16x8*)(wb + nt * 8192 + 512);
#pragma unroll
      for (int nt = 0; nt < 4; ++nt)
#pragma unroll
        for (int mt = 0; mt < 4; ++mt)
          acc[mt][nt + 4] = __builtin_amdgcn_mfma_f32_16x16x32_bf16(a[mt], bB[nt], Z, 0, 0, 0);
#pragma unroll
      for (int mt = 0; mt < 4; ++mt)
        gacc[mt] = __builtin_amdgcn_mfma_f32_16x16x32_bf16(a[mt], g, gacc[mt], 0, 0, 0);
    }
    for (int st = 1; st < 16; ++st) {
      bf16x8 a[4];
#pragma unroll
      for (int mt = 0; mt < 4; ++mt) a[mt] = ldA(mt, st);
#pragma unroll
      for (int nt = 0; nt < 4; ++nt)
        bB[nt] = *(const bf16x8*)(wb + (nt + 4) * 8192 + st * 512);
      bf16x8 g = *(const bf16x8*)(gb + st * 512);
#pragma unroll
      for (int nt = 0; nt < 4; ++nt)
#pragma unroll
        for (int mt = 0; mt < 4; ++mt)
          acc[mt][nt] = __builtin_amdgcn_mfma_f32_16x16x32_bf16(a[mt], bA[nt], acc[mt][nt], 0, 0, 0);
      int sn = (st + 1 < 16) ? st + 1 : 0;
#pragma unroll
      for (int nt = 0; nt < 4; ++nt)
        bA[nt] = *(const bf16x8*)(wb + nt * 8192 + sn * 512);
#pragma unroll
      for (int nt = 0; nt < 4; ++nt)
#pragma unroll
        for (int mt = 0; mt < 4; ++mt)
          acc[mt][nt + 4] = __builtin_amdgcn_mfma_f32_16x16x32_bf16(a[mt], bB[nt], acc[mt][nt + 4], 0, 0, 0);
#pragma unroll
      for (int mt = 0; mt < 4; ++mt)
        gacc[mt] = __builtin_amdgcn_mfma_f32_16x16x32_bf16(a[mt], g, gacc[mt], 0, 0, 0);
    }
  };

  // forward epilogue: a+=bias; z=softplus -> zbuf; s=sigmoid -> slab (nt stores)
  auto fwd_epi = [&](const float* biasp, u64* slab) {
    float bias[8];
#pragma unroll
    for (int nt = 0; nt < 8; ++nt) bias[nt] = biasp[w * 128 + nt * 16 + l15];
#pragma unroll
    for (int mt = 0; mt < 4; ++mt)
#pragma unroll
      for (int nt = 0; nt < 8; ++nt) {
        int n = w * 128 + nt * 16 + l15;
        f32x4 A = acc[mt][nt];
        u64 pack = 0;
#pragma unroll
        for (int r = 0; r < 4; ++r) {
          float a = A[r] + bias[nt];
          float t = __expf(-a);
          float u = 1.0f + t;
          float s = __builtin_amdgcn_rcpf(u);     // sigmoid(a)
          float z = a + __logf(u);                // softplus(a)
          pack |= (u64)f2b(s) << (16 * r);
          wrZ(mt * 16 + q * 4 + r, n, z);
        }
        __builtin_nontemporal_store(pack, &slab[(blk4w * 32 + mt * 8 + nt) * 64 + lane]);
      }
  };
  auto d3_epi = [&](const float* biasp) {   // d3 = WzL * sigmoid(a3) -> zbuf
    float bias[8], wl[8];
#pragma unroll
    for (int nt = 0; nt < 8; ++nt) {
      bias[nt] = biasp[w * 128 + nt * 16 + l15];
      wl[nt] = WzL[w * 128 + nt * 16 + l15];
    }
#pragma unroll
    for (int mt = 0; mt < 4; ++mt)
#pragma unroll
      for (int nt = 0; nt < 8; ++nt) {
        int n = w * 128 + nt * 16 + l15;
        f32x4 A = acc[mt][nt];
#pragma unroll
        for (int r = 0; r < 4; ++r) {
          float a = A[r] + bias[nt];
          float t = __expf(-a);
          float s = __builtin_amdgcn_rcpf(1.0f + t);
          wrZ(mt * 16 + q * 4 + r, n, wl[nt] * s);
        }
      }
  };
  auto bwd_epi = [&](const u64* slab) {     // d = g * s -> zbuf (batched nt loads)
#pragma unroll
    for (int mt = 0; mt < 4; ++mt) {
      u64 v[8];
#pragma unroll
      for (int nt = 0; nt < 8; ++nt)
        v[nt] = __builtin_nontemporal_load(&slab[(blk4w * 32 + mt * 8 + nt) * 64 + lane]);
#pragma unroll
      for (int nt = 0; nt < 8; ++nt) {
        int n = w * 128 + nt * 16 + l15;
        f32x4 A = acc[mt][nt];
#pragma unroll
        for (int r = 0; r < 4; ++r) {
          float s = b2f((u32)(v[nt] >> (16 * r)) & 0xffffu);
          wrZ(mt * 16 + q * 4 + r, n, A[r] * s);
        }
      }
    }
  };

  // ---------------- forward ----------------
  __syncthreads();                          // xbuf ready
  fwdX(Wz0b, true);                         // a0 = x@Wz0^T
  __syncthreads(); fwd_epi(bz0, slab0); __syncthreads();
  fwdH(Wz1b); fwdX(Wx0b, false);            // a1 = z0@Wz1^T + x@Wx0^T
  __syncthreads(); fwd_epi(bx0, slab1); __syncthreads();
  fwdH(Wz2b); fwdX(Wx1b, false);
  __syncthreads(); fwd_epi(bx1, slab2); __syncthreads();
  fwdH(Wz3b); fwdX(Wx2b, false);
  __syncthreads(); d3_epi(bx2); __syncthreads();
  // ---------------- backward ----------------
  bwdH(Wz3t, Wx2t);                         // g2 = d3@Wz3 ; grad += d3@Wx2
  __syncthreads(); bwd_epi(slab2); __syncthreads();
  bwdH(Wz2t, Wx1t);
  __syncthreads(); bwd_epi(slab1); __syncthreads();
  bwdH(Wz1t, Wx0t);
  __syncthreads(); bwd_epi(slab0); __syncthreads();
  {                                         // grad += d0@Wz0 (pipelined g-frags)
    const u16* gb = Wz0t + (w * 16) * 512 + lane * 8;
    bf16x8 g0 = *(const bf16x8*)(gb);
#pragma unroll 2
    for (int st = 0; st < 16; ++st) {
      bf16x8 a[4];
#pragma unroll
      for (int mt = 0; mt < 4; ++mt) a[mt] = ldA(mt, st);
      bf16x8 g1 = *(const bf16x8*)(gb + ((st + 1 < 16) ? st + 1 : 0) * 512);
#pragma unroll
      for (int mt = 0; mt < 4; ++mt)
        gacc[mt] = __builtin_amdgcn_mfma_f32_16x16x32_bf16(a[mt], g0, gacc[mt], 0, 0, 0);
      g0 = g1;
    }
  }
  // store: out[b][d] = gacc + WxL[d]  (non-temporal)
  int n2 = w * 16 + l15;
  float wx = WxL[n2];
#pragma unroll
  for (int mt = 0; mt < 4; ++mt)
#pragma unroll
    for (int r = 0; r < 4; ++r)
      __builtin_nontemporal_store(gacc[mt][r] + wx,
          &out[(blk * BM + mt * 16 + q * 4 + r) * D + n2]);
}

extern "C" void kernel_launch(void* const* d_in, const int* in_sizes, int n_in,
                              void* d_out, int out_size, void* d_ws, size_t ws_size,
                              hipStream_t stream) {
  const float* state = (const float*)d_in[0];
  const float* Wz0 = (const float*)d_in[1];
  const float* bz0 = (const float*)d_in[2];
  const float* Wz1 = (const float*)d_in[3];
  const float* Wz2 = (const float*)d_in[4];
  const float* Wz3 = (const float*)d_in[5];
  const float* WzL = (const float*)d_in[6];
  const float* Wx0 = (const float*)d_in[7];
  const float* bx0 = (const float*)d_in[8];
  const float* Wx1 = (const float*)d_in[9];
  const float* bx1 = (const float*)d_in[10];
  const float* Wx2 = (const float*)d_in[11];
  const float* bx2 = (const float*)d_in[12];
  const float* WxL = (const float*)d_in[13];

  if (ws_size < (size_t)WS_ELEMS * 2) {
    fill_sentinel<<<(out_size + 255) / 256, 256, 0, stream>>>((float*)d_out, out_size);
    return;
  }
  u16* wsw = (u16*)d_ws;
  prep_kernel<<<OFF_WEND / 256, 256, 0, stream>>>(Wz0, Wz1, Wz2, Wz3, Wx0, Wx1, Wx2, wsw);
  icnn_kernel<<<B_TOTAL / BM, 256, 0, stream>>>(state, bz0, bx0, bx1, bx2, WzL, WxL,
                                                wsw, (float*)d_out);
}